// Round 5
// baseline (357.506 us; speedup 1.0000x reference)
//
#include <hip/hip_runtime.h>
#include <hip/hip_bf16.h>

typedef __attribute__((ext_vector_type(8))) short short8;
typedef __attribute__((ext_vector_type(4))) short short4v;
typedef __attribute__((ext_vector_type(4))) float f32x4;
typedef __attribute__((ext_vector_type(2))) float f32x2;

__device__ __forceinline__ unsigned short f2bf(float f) {
    unsigned int u = __builtin_bit_cast(unsigned int, f);
    u += 0x7fffu + ((u >> 16) & 1u);   // round-to-nearest-even
    return (unsigned short)(u >> 16);
}
__device__ __forceinline__ unsigned int pack2(float a, float b) {
    union { __hip_bfloat162 h; unsigned int u; } r;
    r.h = __float22bfloat162_rn(make_float2(a, b));
    return r.u;
}
__device__ __forceinline__ short4v cvt4(float a, float b, float c, float d) {
    union { __hip_bfloat162 h[2]; short4v s; } u;
    u.h[0] = __float22bfloat162_rn(make_float2(a, b));
    u.h[1] = __float22bfloat162_rn(make_float2(c, d));
    return u.s;
}

// ---------------------------------------------------------------------------
// Kernel A: partial adjacency sums over 60-frame chunks. grid (5,32).
// ---------------------------------------------------------------------------
__global__ void kA(const float* __restrict__ xx, float* __restrict__ At_part) {
    __shared__ float xs3[3][60][25];
    const int tc = blockIdx.x, n = blockIdx.y;
    const int tid = threadIdx.x;
    const float* base = xx + (size_t)n * 22500 + tc * 1500;
    for (int idx = tid; idx < 4500; idx += 256) {
        int ch = idx / 1500, rt = idx % 1500;
        xs3[ch][rt / 25][rt % 25] = base[ch * 7500 + rt];
    }
    __syncthreads();
    for (int p = tid; p < 625; p += 256) {
        int v = p / 25, u = p % 25;
        float s = 0.f;
        for (int t = 0; t < 60; ++t) {
            float dx = xs3[0][t][v] - xs3[0][t][u];
            float dy = xs3[1][t][v] - xs3[1][t][u];
            float dz = xs3[2][t][v] - xs3[2][t][u];
            s += __expf(-2.f * (dx * dx + dy * dy + dz * dz));
        }
        At_part[(size_t)(n * 5 + tc) * 625 + p] = s;
    }
}

// ---------------------------------------------------------------------------
// Kernel B1: per-sample reduce + symmetric normalization. grid 32.
// ---------------------------------------------------------------------------
__global__ void kB1(const float* __restrict__ At_part, float* __restrict__ Acontrib) {
    __shared__ float At[625];
    __shared__ float dinv[25];
    const int n = blockIdx.x, tid = threadIdx.x;
    for (int p = tid; p < 625; p += 256) {
        float s = 0.f;
        for (int tc = 0; tc < 5; ++tc) s += At_part[(size_t)(n * 5 + tc) * 625 + p];
        At[p] = s;
    }
    __syncthreads();
    if (tid < 25) {
        float d = 0.f;
        for (int u = 0; u < 25; ++u) d += At[tid * 25 + u];
        dinv[tid] = rsqrtf(d * (1.f / 300.f));
    }
    __syncthreads();
    for (int p = tid; p < 625; p += 256)
        Acontrib[n * 625 + p] = At[p] * (1.f / 300.f) * dinv[p / 25] * dinv[p % 25] * (1.f / 32.f);
}

// ---------------------------------------------------------------------------
// Kernel B2: block 0 -> bsTg (bf16 [64][72], zero-padded) + fused bias;
//            blocks 1..36 -> W'' = W * bn_scale.
// ---------------------------------------------------------------------------
__global__ void kB2(const float* __restrict__ Acontrib, const float* __restrict__ A_res,
                    const float* __restrict__ W, const float* __restrict__ b,
                    const float* __restrict__ gamma, const float* __restrict__ beta,
                    const float* __restrict__ rm, const float* __restrict__ rv,
                    short* __restrict__ bsTg, short* __restrict__ Wpg,
                    float* __restrict__ bbg) {
    const int tid = threadIdx.x;
    if (blockIdx.x == 0) {
        __shared__ float macc[625];
        for (int p = tid; p < 625; p += 256) {
            float s = 0.f;
            for (int n = 0; n < 32; ++n) s += Acontrib[n * 625 + p];
            macc[p] = s;
        }
        __syncthreads();
        for (int idx = tid; idx < 64 * 72; idx += 256) {
            int col = idx / 72, u = idx % 72;
            float v = 0.f;
            if (col < 50 && u < 50) v = macc[(col % 25) * 25 + (u % 25)] + A_res[col * 50 + u];
            bsTg[idx] = (short)f2bf(v);
        }
        if (tid < 192) {
            float sc = gamma[tid] * rsqrtf(rv[tid] + 1e-5f);
            bbg[tid] = b[tid] * sc + beta[tid] - rm[tid] * sc;
        }
    } else {
        const int e = (blockIdx.x - 1) * 1024 + tid * 4;
        const int o = e / 192;
        const float sc = gamma[o] * rsqrtf(rv[o] + 1e-5f);
        float4 w = *(const float4*)(W + e);
        short4v s4 = { (short)f2bf(w.x * sc), (short)f2bf(w.y * sc),
                       (short)f2bf(w.z * sc), (short)f2bf(w.w * sc) };
        *(short4v*)(Wpg + e) = s4;
    }
}

// ---------------------------------------------------------------------------
// Kernel C helpers: per-timestep stage with depth-1 register prefetch.
// One t = 96 rows x 50 floats = 2400 float2.
// ---------------------------------------------------------------------------
__device__ __forceinline__ void ldpair(const float* __restrict__ x, int gbase,
                                       f32x2 (&pf)[10], int tid) {
#pragma unroll
    for (int i = 0; i < 10; ++i) {
        int idx = i * 256 + tid;
        idx = idx < 2400 ? idx : 2399;
        int c = idx / 25, q = idx - c * 25;
        pf[i] = *(const f32x2*)(x + gbase + (size_t)c * 15000 + 2 * q);
    }
}
__device__ __forceinline__ void stpair(char* xsb, int slot, const f32x2 (&pf)[10], int tid) {
#pragma unroll
    for (int i = 0; i < 10; ++i) {
        int idx = i * 256 + tid;
        if (idx < 2400) {
            int c = idx / 25, q = idx - c * 25;
            *(unsigned int*)(xsb + ((slot * 12288 + c * 128 + 4 * q) ^ ((c & 7) << 4)))
                = pack2(pf[i].x, pf[i].y);
        }
    }
}

// ---------------------------------------------------------------------------
// Kernel C: fused graph-conv + 1x1 conv + BN + ReLU.
// grid 2400 linear, XCD-swizzled: xcd owns 4 consecutive n x all t-chunks.
// 4 timesteps per block, per-t pipelined stage (2-slot xsb, depth-1 prefetch).
// LDS: xs 24576 + a2T 10000 + bias 768 = 35.3 KB -> 4 blocks/CU.
// ---------------------------------------------------------------------------
__global__ __launch_bounds__(256, 4)
void kC(const float* __restrict__ x, const short* __restrict__ Wpg,
        const short* __restrict__ bsTg, const float* __restrict__ bbg,
        float* __restrict__ out) {
    __shared__ __align__(16) char xsb[2 * 96 * 128];   // 24576 B (2 t-slots)
    __shared__ __align__(16) short a2T[25][200];       // 10000 B
    __shared__ float bbs[192];

    const int tid = threadIdx.x;
    const int lane = tid & 63;
    const int wid = tid >> 6;
    const int lam = lane & 15;
    const int kc = (lane >> 4) * 8;
    const int cb = (lane >> 4) * 4;

    // XCD-aware swizzle: 2400 blocks, 300 per XCD, t-chunk fastest.
    const int bid = blockIdx.x;
    const int lg = (bid & 7) * 300 + (bid >> 3);
    const int n = lg / 75;
    const int tc = lg - n * 75;
    const int t0 = tc * 4;
    const int gb0 = n * 1440000 + t0 * 50;

    // prefetch t0 into regs first (longest latency first)
    f32x2 pf[10];
    ldpair(x, gb0, pf, tid);

    // W'' fragments: wave owns output rows [wid*48, wid*48+48)
    const int r0 = wid * 48 + lam;
    short8 wf[3][6];
#pragma unroll
    for (int mt = 0; mt < 3; ++mt)
#pragma unroll
        for (int ks = 0; ks < 6; ++ks)
            wf[mt][ks] = *(const short8*)(Wpg + (r0 + mt * 16) * 192 + ks * 32 + kc);

    // A_scale (GEMM1 B) fragments in registers
    const int ncol = wid * 16 + lam;
    const short8 bq0 = *(const short8*)(bsTg + ncol * 72 + kc);
    const short8 bq1 = *(const short8*)(bsTg + ncol * 72 + 32 + kc);

    if (tid < 192) bbs[tid] = bbg[tid];

    // zero the u=50..63 pad once for both slots
    for (int idx = tid; idx < 1344; idx += 256) {
        int r = idx / 7, k = idx - r * 7;
        int slot = r / 96, c = r - 96 * slot;
        *(unsigned int*)(xsb + ((slot * 12288 + c * 128 + (50 + 2 * k) * 2) ^ ((c & 7) << 4))) = 0;
    }

    stpair(xsb, 0, pf, tid);       // t0 -> slot0
    ldpair(x, gb0 + 50, pf, tid);  // issue t1
    __syncthreads();

    const f32x4 z = {0.f, 0.f, 0.f, 0.f};
    const int s = ncol >= 25 ? 1 : 0;
    const int vs = ncol - 25 * s;

#pragma unroll 1
    for (int tl = 0; tl < 4; ++tl) {
        const int slot = tl & 1;
        // ---- GEMM1: agg(96x50) for timestep t0+tl ----
        f32x4 acc1[6];
#pragma unroll
        for (int mt = 0; mt < 6; ++mt) acc1[mt] = z;
#pragma unroll
        for (int ks = 0; ks < 2; ++ks) {
#pragma unroll
            for (int mt = 0; mt < 6; ++mt) {
                int c = mt * 16 + lam;
                const short8 afr = *(const short8*)(xsb +
                    ((slot * 12288 + c * 128 + (ks * 32 + kc) * 2) ^ ((c & 7) << 4)));
                acc1[mt] = __builtin_amdgcn_mfma_f32_16x16x32_bf16(
                    afr, ks ? bq1 : bq0, acc1[mt], 0, 0, 0);
            }
        }
        if (ncol < 50) {
#pragma unroll
            for (int mt = 0; mt < 6; ++mt)
                *(short4v*)(&a2T[vs][s * 96 + mt * 16 + cb]) =
                    cvt4(acc1[mt][0], acc1[mt][1], acc1[mt][2], acc1[mt][3]);
        }
        if (tl < 3) stpair(xsb, slot ^ 1, pf, tid);   // next t -> other slot
        __syncthreads();
        if (tl < 2) ldpair(x, gb0 + (tl + 2) * 50, pf, tid);  // issue t+2

        // ---- GEMM2: out(192x25) for this timestep ----
        f32x4 acc[3][2];
#pragma unroll
        for (int mt = 0; mt < 3; ++mt) { acc[mt][0] = z; acc[mt][1] = z; }
        const int c1 = (16 + lam) < 25 ? (16 + lam) : 24;
#pragma unroll
        for (int ks = 0; ks < 6; ++ks) {
            const short8 B0 = *(const short8*)(&a2T[lam][ks * 32 + kc]);
            const short8 B1 = *(const short8*)(&a2T[c1][ks * 32 + kc]);
#pragma unroll
            for (int mt = 0; mt < 3; ++mt) {
                acc[mt][0] = __builtin_amdgcn_mfma_f32_16x16x32_bf16(wf[mt][ks], B0, acc[mt][0], 0, 0, 0);
                acc[mt][1] = __builtin_amdgcn_mfma_f32_16x16x32_bf16(wf[mt][ks], B1, acc[mt][1], 0, 0, 0);
            }
        }
        const int t = t0 + tl;
#pragma unroll
        for (int nt = 0; nt < 2; ++nt) {
            const int col = nt * 16 + lam;
            if (col < 25) {
#pragma unroll
                for (int mt = 0; mt < 3; ++mt) {
                    const int ob = wid * 48 + mt * 16 + cb;
                    float* op = out + ((size_t)(n * 192 + ob) * 300 + t) * 25 + col;
#pragma unroll
                    for (int r = 0; r < 4; ++r) {
                        float v = acc[mt][nt][r] + bbs[ob + r];
                        op[(size_t)r * 7500] = v > 0.f ? v : 0.f;
                    }
                }
            }
        }
        if (tl < 3) __syncthreads();   // a2T WAR + next-slot ready
    }
}

// ---------------------------------------------------------------------------
extern "C" void kernel_launch(void* const* d_in, const int* in_sizes, int n_in,
                              void* d_out, int out_size, void* d_ws, size_t ws_size,
                              hipStream_t stream) {
    const float* x     = (const float*)d_in[0];
    const float* xx    = (const float*)d_in[1];
    const float* A_res = (const float*)d_in[2];
    const float* W     = (const float*)d_in[3];
    const float* b     = (const float*)d_in[4];
    const float* gamma = (const float*)d_in[5];
    const float* beta  = (const float*)d_in[6];
    const float* rm    = (const float*)d_in[7];
    const float* rv    = (const float*)d_in[8];
    float* out = (float*)d_out;

    char* ws = (char*)d_ws;
    float* At_part  = (float*)ws;                    // 160*625*4 = 400000 B
    float* Acontrib = (float*)(ws + 400000);         // 32*625*4  =  80000 B
    short* bsTg     = (short*)(ws + 480000);         // 64*72*2   =   9216 B
    short* Wpg      = (short*)(ws + 489216);         // 192*192*2 =  73728 B
    float* bbg      = (float*)(ws + 562944);         // 192*4     =    768 B

    kA<<<dim3(5, 32), 256, 0, stream>>>(xx, At_part);
    kB1<<<32, 256, 0, stream>>>(At_part, Acontrib);
    kB2<<<37, 256, 0, stream>>>(Acontrib, A_res, W, b, gamma, beta, rm, rv, bsTg, Wpg, bbg);
    kC<<<2400, 256, 0, stream>>>(x, Wpg, bsTg, bbg, out);
}

// Round 6
// 316.264 us; speedup vs baseline: 1.1304x; 1.1304x over previous
//
#include <hip/hip_runtime.h>
#include <hip/hip_bf16.h>

typedef __attribute__((ext_vector_type(8))) short short8;
typedef __attribute__((ext_vector_type(4))) short short4v;
typedef __attribute__((ext_vector_type(4))) float f32x4;
typedef __attribute__((ext_vector_type(2))) float f32x2;

__device__ __forceinline__ unsigned short f2bf(float f) {
    unsigned int u = __builtin_bit_cast(unsigned int, f);
    u += 0x7fffu + ((u >> 16) & 1u);   // round-to-nearest-even
    return (unsigned short)(u >> 16);
}
__device__ __forceinline__ unsigned int pack2(float a, float b) {
    union { __hip_bfloat162 h; unsigned int u; } r;
    r.h = __float22bfloat162_rn(make_float2(a, b));
    return r.u;
}
__device__ __forceinline__ short4v cvt4(float a, float b, float c, float d) {
    union { __hip_bfloat162 h[2]; short4v s; } u;
    u.h[0] = __float22bfloat162_rn(make_float2(a, b));
    u.h[1] = __float22bfloat162_rn(make_float2(c, d));
    return u.s;
}

// ---------------------------------------------------------------------------
// Kernel A: partial adjacency sums over 60-frame chunks. grid (5,32).
// ---------------------------------------------------------------------------
__global__ void kA(const float* __restrict__ xx, float* __restrict__ At_part) {
    __shared__ float xs3[3][60][25];
    const int tc = blockIdx.x, n = blockIdx.y;
    const int tid = threadIdx.x;
    const float* base = xx + (size_t)n * 22500 + tc * 1500;
    for (int idx = tid; idx < 4500; idx += 256) {
        int ch = idx / 1500, rt = idx % 1500;
        xs3[ch][rt / 25][rt % 25] = base[ch * 7500 + rt];
    }
    __syncthreads();
    for (int p = tid; p < 625; p += 256) {
        int v = p / 25, u = p % 25;
        float s = 0.f;
        for (int t = 0; t < 60; ++t) {
            float dx = xs3[0][t][v] - xs3[0][t][u];
            float dy = xs3[1][t][v] - xs3[1][t][u];
            float dz = xs3[2][t][v] - xs3[2][t][u];
            s += __expf(-2.f * (dx * dx + dy * dy + dz * dz));
        }
        At_part[(size_t)(n * 5 + tc) * 625 + p] = s;
    }
}

// ---------------------------------------------------------------------------
// Kernel B1: per-sample reduce + symmetric normalization. grid 32.
// ---------------------------------------------------------------------------
__global__ void kB1(const float* __restrict__ At_part, float* __restrict__ Acontrib) {
    __shared__ float At[625];
    __shared__ float dinv[25];
    const int n = blockIdx.x, tid = threadIdx.x;
    for (int p = tid; p < 625; p += 256) {
        float s = 0.f;
        for (int tc = 0; tc < 5; ++tc) s += At_part[(size_t)(n * 5 + tc) * 625 + p];
        At[p] = s;
    }
    __syncthreads();
    if (tid < 25) {
        float d = 0.f;
        for (int u = 0; u < 25; ++u) d += At[tid * 25 + u];
        dinv[tid] = rsqrtf(d * (1.f / 300.f));
    }
    __syncthreads();
    for (int p = tid; p < 625; p += 256)
        Acontrib[n * 625 + p] = At[p] * (1.f / 300.f) * dinv[p / 25] * dinv[p % 25] * (1.f / 32.f);
}

// ---------------------------------------------------------------------------
// Kernel B2: block 0 -> bsTg (bf16 [64][72], zero-padded) + fused bias;
//            blocks 1..36 -> W'' = W * bn_scale  (layout [o][k], row-major).
// ---------------------------------------------------------------------------
__global__ void kB2(const float* __restrict__ Acontrib, const float* __restrict__ A_res,
                    const float* __restrict__ W, const float* __restrict__ b,
                    const float* __restrict__ gamma, const float* __restrict__ beta,
                    const float* __restrict__ rm, const float* __restrict__ rv,
                    short* __restrict__ bsTg, short* __restrict__ Wpg,
                    float* __restrict__ bbg) {
    const int tid = threadIdx.x;
    if (blockIdx.x == 0) {
        __shared__ float macc[625];
        for (int p = tid; p < 625; p += 256) {
            float s = 0.f;
            for (int n = 0; n < 32; ++n) s += Acontrib[n * 625 + p];
            macc[p] = s;
        }
        __syncthreads();
        for (int idx = tid; idx < 64 * 72; idx += 256) {
            int col = idx / 72, u = idx % 72;
            float v = 0.f;
            if (col < 50 && u < 50) v = macc[(col % 25) * 25 + (u % 25)] + A_res[col * 50 + u];
            bsTg[idx] = (short)f2bf(v);
        }
        if (tid < 192) {
            float sc = gamma[tid] * rsqrtf(rv[tid] + 1e-5f);
            bbg[tid] = b[tid] * sc + beta[tid] - rm[tid] * sc;
        }
    } else {
        const int e = (blockIdx.x - 1) * 1024 + tid * 4;
        const int o = e / 192;
        const float sc = gamma[o] * rsqrtf(rv[o] + 1e-5f);
        float4 w = *(const float4*)(W + e);
        short4v s4 = { (short)f2bf(w.x * sc), (short)f2bf(w.y * sc),
                       (short)f2bf(w.z * sc), (short)f2bf(w.w * sc) };
        *(short4v*)(Wpg + e) = s4;
    }
}

// ---------------------------------------------------------------------------
// Kernel C helpers: one timestep = 96 rows x 50 floats = 2400 f32x2.
// ---------------------------------------------------------------------------
__device__ __forceinline__ void ldpair(const float* __restrict__ x, int gbase,
                                       f32x2 (&pf)[10], int tid) {
#pragma unroll
    for (int i = 0; i < 10; ++i) {
        int idx = i * 256 + tid;
        idx = idx < 2400 ? idx : 2399;
        int c = idx / 25, q = idx - c * 25;
        pf[i] = *(const f32x2*)(x + gbase + (size_t)c * 15000 + 2 * q);
    }
}
__device__ __forceinline__ void stpair(char* xsb, int slot, const f32x2 (&pf)[10], int tid) {
#pragma unroll
    for (int i = 0; i < 10; ++i) {
        int idx = i * 256 + tid;
        if (idx < 2400) {
            int c = idx / 25, q = idx - c * 25;
            *(unsigned int*)(xsb + ((slot * 12288 + c * 128 + 4 * q) ^ ((c & 7) << 4)))
                = pack2(pf[i].x, pf[i].y);
        }
    }
}

// ---------------------------------------------------------------------------
// Kernel C: fused graph-conv + 1x1 conv + BN + ReLU.
// grid (75, 32) natural order (adjacent tc co-scheduled -> sector sharing
// absorbed in L2/L3).  4 timesteps/block, 2-slot per-t staging pipeline.
// GEMM2 flipped: D[tv][o] so each lane stores 4 CONSECUTIVE floats.
// LDS: xs 24576 + a2T[32][200] 12800 = 37.4 KB -> 4 blocks/CU.
// ---------------------------------------------------------------------------
__global__ __launch_bounds__(256, 4)
void kC(const float* __restrict__ x, const short* __restrict__ Wpg,
        const short* __restrict__ bsTg, const float* __restrict__ bbg,
        float* __restrict__ out) {
    __shared__ __align__(16) char xsb[2 * 96 * 128];   // 24576 B (2 t-slots)
    __shared__ __align__(16) short a2T[32][200];       // 12800 B (rows 25..31 pad)

    const int tid = threadIdx.x;
    const int lane = tid & 63;
    const int wid = tid >> 6;
    const int lam = lane & 15;
    const int kc = (lane >> 4) * 8;
    const int cb = (lane >> 4) * 4;
    const int n = blockIdx.y;
    const int t0 = blockIdx.x * 4;
    const int gb0 = n * 1440000 + t0 * 50;

    // prefetch t0 (longest latency first)
    f32x2 pf[10];
    ldpair(x, gb0, pf, tid);

    // W'' fragments (serve as GEMM2 B-fragments: col o = wid*48+mt*16+lam)
    const int r0 = wid * 48 + lam;
    short8 wf[3][6];
#pragma unroll
    for (int mt = 0; mt < 3; ++mt)
#pragma unroll
        for (int ks = 0; ks < 6; ++ks)
            wf[mt][ks] = *(const short8*)(Wpg + (r0 + mt * 16) * 192 + ks * 32 + kc);

    // A_scale (GEMM1 B) fragments
    const int ncol = wid * 16 + lam;
    const short8 bq0 = *(const short8*)(bsTg + ncol * 72 + kc);
    const short8 bq1 = *(const short8*)(bsTg + ncol * 72 + 32 + kc);

    // per-lane fused bias (o = r0 + mt*16)
    float bb[3];
#pragma unroll
    for (int mt = 0; mt < 3; ++mt) bb[mt] = bbg[r0 + mt * 16];

    // zero the u=50..63 pad once (stage never touches it)
    for (int idx = tid; idx < 1344; idx += 256) {
        int r = idx / 7, k = idx - r * 7;
        int slot = r / 96, c = r - 96 * slot;
        *(unsigned int*)(xsb + ((slot * 12288 + c * 128 + (50 + 2 * k) * 2) ^ ((c & 7) << 4))) = 0;
    }

    stpair(xsb, 0, pf, tid);        // t0 -> slot0
    ldpair(x, gb0 + 50, pf, tid);   // t1
    stpair(xsb, 1, pf, tid);        // t1 -> slot1
    ldpair(x, gb0 + 100, pf, tid);  // t2 in flight
    __syncthreads();

    const f32x4 z = {0.f, 0.f, 0.f, 0.f};
    const int s = ncol >= 25 ? 1 : 0;
    const int vs = ncol - 25 * s;

#pragma unroll 1
    for (int tl = 0; tl < 4; ++tl) {
        const int slot = tl & 1;
        // ---- GEMM1: agg(96x50) for timestep t0+tl ----
        f32x4 acc1[6];
#pragma unroll
        for (int mt = 0; mt < 6; ++mt) acc1[mt] = z;
#pragma unroll
        for (int ks = 0; ks < 2; ++ks) {
#pragma unroll
            for (int mt = 0; mt < 6; ++mt) {
                int c = mt * 16 + lam;
                const short8 afr = *(const short8*)(xsb +
                    ((slot * 12288 + c * 128 + (ks * 32 + kc) * 2) ^ ((c & 7) << 4)));
                acc1[mt] = __builtin_amdgcn_mfma_f32_16x16x32_bf16(
                    afr, ks ? bq1 : bq0, acc1[mt], 0, 0, 0);
            }
        }
        if (ncol < 50) {
#pragma unroll
            for (int mt = 0; mt < 6; ++mt)
                *(short4v*)(&a2T[vs][s * 96 + mt * 16 + cb]) =
                    cvt4(acc1[mt][0], acc1[mt][1], acc1[mt][2], acc1[mt][3]);
        }
        __syncthreads();

        // ---- GEMM2 (flipped): D[tv][o] = agg2^T x W''^T for this timestep ----
        f32x4 acc[3][2];
#pragma unroll
        for (int mt = 0; mt < 3; ++mt) { acc[mt][0] = z; acc[mt][1] = z; }
#pragma unroll
        for (int ks = 0; ks < 6; ++ks) {
            const short8 A0 = *(const short8*)(&a2T[lam][ks * 32 + kc]);        // tv 0..15
            const short8 A1 = *(const short8*)(&a2T[16 + lam][ks * 32 + kc]);   // tv 16..31
#pragma unroll
            for (int mt = 0; mt < 3; ++mt) {
                acc[mt][0] = __builtin_amdgcn_mfma_f32_16x16x32_bf16(A0, wf[mt][ks], acc[mt][0], 0, 0, 0);
                acc[mt][1] = __builtin_amdgcn_mfma_f32_16x16x32_bf16(A1, wf[mt][ks], acc[mt][1], 0, 0, 0);
            }
        }

        // restage pipeline: t+2 into this slot; issue load of t+3
        if (tl < 2) stpair(xsb, slot, pf, tid);
        if (tl == 0) ldpair(x, gb0 + 150, pf, tid);

        // ---- epilogue: contiguous per-lane stores ----
        const int t = t0 + tl;
#pragma unroll
        for (int mt = 0; mt < 3; ++mt) {
            float* op = out + ((size_t)(n * 192 + r0 + mt * 16)) * 7500 + t * 25;
#pragma unroll
            for (int r = 0; r < 4; ++r) {               // tv = cb+r (<25 always)
                float v = acc[mt][0][r] + bb[mt];
                op[cb + r] = v > 0.f ? v : 0.f;
            }
#pragma unroll
            for (int r = 0; r < 4; ++r) {               // tv = 16+cb+r
                int tv = 16 + cb + r;
                if (tv < 25) {
                    float v = acc[mt][1][r] + bb[mt];
                    op[tv] = v > 0.f ? v : 0.f;
                }
            }
        }
        if (tl < 3) __syncthreads();   // a2T WAR + restaged slot visibility
    }
}

// ---------------------------------------------------------------------------
extern "C" void kernel_launch(void* const* d_in, const int* in_sizes, int n_in,
                              void* d_out, int out_size, void* d_ws, size_t ws_size,
                              hipStream_t stream) {
    const float* x     = (const float*)d_in[0];
    const float* xx    = (const float*)d_in[1];
    const float* A_res = (const float*)d_in[2];
    const float* W     = (const float*)d_in[3];
    const float* b     = (const float*)d_in[4];
    const float* gamma = (const float*)d_in[5];
    const float* beta  = (const float*)d_in[6];
    const float* rm    = (const float*)d_in[7];
    const float* rv    = (const float*)d_in[8];
    float* out = (float*)d_out;

    char* ws = (char*)d_ws;
    float* At_part  = (float*)ws;                    // 160*625*4 = 400000 B
    float* Acontrib = (float*)(ws + 400000);         // 32*625*4  =  80000 B
    short* bsTg     = (short*)(ws + 480000);         // 64*72*2   =   9216 B
    short* Wpg      = (short*)(ws + 489216);         // 192*192*2 =  73728 B
    float* bbg      = (float*)(ws + 562944);         // 192*4     =    768 B

    kA<<<dim3(5, 32), 256, 0, stream>>>(xx, At_part);
    kB1<<<32, 256, 0, stream>>>(At_part, Acontrib);
    kB2<<<37, 256, 0, stream>>>(Acontrib, A_res, W, b, gamma, beta, rm, rv, bsTg, Wpg, bbg);
    kC<<<dim3(75, 32), 256, 0, stream>>>(x, Wpg, bsTg, bbg, out);
}

// Round 7
// 266.422 us; speedup vs baseline: 1.3419x; 1.1871x over previous
//
#include <hip/hip_runtime.h>
#include <hip/hip_bf16.h>

typedef __attribute__((ext_vector_type(8))) short short8;
typedef __attribute__((ext_vector_type(4))) short short4v;
typedef __attribute__((ext_vector_type(4))) float f32x4;
typedef __attribute__((ext_vector_type(2))) float f32x2;

__device__ __forceinline__ unsigned short f2bf(float f) {
    unsigned int u = __builtin_bit_cast(unsigned int, f);
    u += 0x7fffu + ((u >> 16) & 1u);   // round-to-nearest-even
    return (unsigned short)(u >> 16);
}
__device__ __forceinline__ unsigned int pack2(float a, float b) {
    union { __hip_bfloat162 h; unsigned int u; } r;
    r.h = __float22bfloat162_rn(make_float2(a, b));
    return r.u;
}
__device__ __forceinline__ short4v cvt4(float a, float b, float c, float d) {
    union { __hip_bfloat162 h[2]; short4v s; } u;
    u.h[0] = __float22bfloat162_rn(make_float2(a, b));
    u.h[1] = __float22bfloat162_rn(make_float2(c, d));
    return u.s;
}

// ---------------------------------------------------------------------------
// Kernel A: partial adjacency sums over 60-frame chunks. grid (5,32).
// ---------------------------------------------------------------------------
__global__ void kA(const float* __restrict__ xx, float* __restrict__ At_part) {
    __shared__ float xs3[3][60][25];
    const int tc = blockIdx.x, n = blockIdx.y;
    const int tid = threadIdx.x;
    const float* base = xx + (size_t)n * 22500 + tc * 1500;
    for (int idx = tid; idx < 4500; idx += 256) {
        int ch = idx / 1500, rt = idx % 1500;
        xs3[ch][rt / 25][rt % 25] = base[ch * 7500 + rt];
    }
    __syncthreads();
    for (int p = tid; p < 625; p += 256) {
        int v = p / 25, u = p % 25;
        float s = 0.f;
        for (int t = 0; t < 60; ++t) {
            float dx = xs3[0][t][v] - xs3[0][t][u];
            float dy = xs3[1][t][v] - xs3[1][t][u];
            float dz = xs3[2][t][v] - xs3[2][t][u];
            s += __expf(-2.f * (dx * dx + dy * dy + dz * dz));
        }
        At_part[(size_t)(n * 5 + tc) * 625 + p] = s;
    }
}

// ---------------------------------------------------------------------------
// Kernel B1: per-sample reduce + symmetric normalization. grid 32.
// ---------------------------------------------------------------------------
__global__ void kB1(const float* __restrict__ At_part, float* __restrict__ Acontrib) {
    __shared__ float At[625];
    __shared__ float dinv[25];
    const int n = blockIdx.x, tid = threadIdx.x;
    for (int p = tid; p < 625; p += 256) {
        float s = 0.f;
        for (int tc = 0; tc < 5; ++tc) s += At_part[(size_t)(n * 5 + tc) * 625 + p];
        At[p] = s;
    }
    __syncthreads();
    if (tid < 25) {
        float d = 0.f;
        for (int u = 0; u < 25; ++u) d += At[tid * 25 + u];
        dinv[tid] = rsqrtf(d * (1.f / 300.f));
    }
    __syncthreads();
    for (int p = tid; p < 625; p += 256)
        Acontrib[n * 625 + p] = At[p] * (1.f / 300.f) * dinv[p / 25] * dinv[p % 25] * (1.f / 32.f);
}

// ---------------------------------------------------------------------------
// Kernel B2: block 0 -> bsTg (bf16 [64][72], zero-padded) + fused bias;
//            blocks 1..36 -> W'' = W * bn_scale  (layout [o][k], row-major).
// ---------------------------------------------------------------------------
__global__ void kB2(const float* __restrict__ Acontrib, const float* __restrict__ A_res,
                    const float* __restrict__ W, const float* __restrict__ b,
                    const float* __restrict__ gamma, const float* __restrict__ beta,
                    const float* __restrict__ rm, const float* __restrict__ rv,
                    short* __restrict__ bsTg, short* __restrict__ Wpg,
                    float* __restrict__ bbg) {
    const int tid = threadIdx.x;
    if (blockIdx.x == 0) {
        __shared__ float macc[625];
        for (int p = tid; p < 625; p += 256) {
            float s = 0.f;
            for (int n = 0; n < 32; ++n) s += Acontrib[n * 625 + p];
            macc[p] = s;
        }
        __syncthreads();
        for (int idx = tid; idx < 64 * 72; idx += 256) {
            int col = idx / 72, u = idx % 72;
            float v = 0.f;
            if (col < 50 && u < 50) v = macc[(col % 25) * 25 + (u % 25)] + A_res[col * 50 + u];
            bsTg[idx] = (short)f2bf(v);
        }
        if (tid < 192) {
            float sc = gamma[tid] * rsqrtf(rv[tid] + 1e-5f);
            bbg[tid] = b[tid] * sc + beta[tid] - rm[tid] * sc;
        }
    } else {
        const int e = (blockIdx.x - 1) * 1024 + tid * 4;
        const int o = e / 192;
        const float sc = gamma[o] * rsqrtf(rv[o] + 1e-5f);
        float4 w = *(const float4*)(W + e);
        short4v s4 = { (short)f2bf(w.x * sc), (short)f2bf(w.y * sc),
                       (short)f2bf(w.z * sc), (short)f2bf(w.w * sc) };
        *(short4v*)(Wpg + e) = s4;
    }
}

// ---------------------------------------------------------------------------
// Kernel C helpers: one timestep = 96 rows x 50 floats = 2400 f32x2.
// ---------------------------------------------------------------------------
__device__ __forceinline__ void ldpair(const float* __restrict__ x, int gbase,
                                       f32x2 (&pf)[10], int tid) {
#pragma unroll
    for (int i = 0; i < 10; ++i) {
        int idx = i * 256 + tid;
        idx = idx < 2400 ? idx : 2399;
        int c = idx / 25, q = idx - c * 25;
        pf[i] = *(const f32x2*)(x + gbase + (size_t)c * 15000 + 2 * q);
    }
}
__device__ __forceinline__ void stpair(char* xsb, int slot, const f32x2 (&pf)[10], int tid) {
#pragma unroll
    for (int i = 0; i < 10; ++i) {
        int idx = i * 256 + tid;
        if (idx < 2400) {
            int c = idx / 25, q = idx - c * 25;
            *(unsigned int*)(xsb + ((slot * 12288 + c * 128 + 4 * q) ^ ((c & 7) << 4)))
                = pack2(pf[i].x, pf[i].y);
        }
    }
}

// ---------------------------------------------------------------------------
// Kernel C: fused graph-conv + 1x1 conv + BN + ReLU.
// grid (75, 32) natural order.  4 timesteps/block, 2-slot per-t staging
// (issue loads early / LDS-write late, T14).  Flipped GEMM2 -> each lane
// stores contiguous dwordx4.  LDS 37.4 KB; __launch_bounds__(256,3) gives a
// 170-VGPR budget so wf/bq/pf preloads DO NOT SPILL (the R4-R6 failure).
// ---------------------------------------------------------------------------
__global__ __launch_bounds__(256, 3)
void kC(const float* __restrict__ x, const short* __restrict__ Wpg,
        const short* __restrict__ bsTg, const float* __restrict__ bbg,
        float* __restrict__ out) {
    __shared__ __align__(16) char xsb[2 * 12288];      // 2 one-timestep slots
    __shared__ __align__(16) short a2T[32][200];       // 12800 B (rows 25..31 pad)

    const int tid = threadIdx.x;
    const int lane = tid & 63;
    const int wid = tid >> 6;
    const int lam = lane & 15;
    const int kc = (lane >> 4) * 8;
    const int cb = (lane >> 4) * 4;
    const int n = blockIdx.y;
    const int t0 = blockIdx.x * 4;
    const int gb0 = n * 1440000 + t0 * 50;

    // prefetch t0 (longest latency first)
    f32x2 pf[10];
    ldpair(x, gb0, pf, tid);

    // W'' fragments (GEMM2 B-operand: col o = wid*48 + mt*16 + lam)
    const int r0 = wid * 48 + lam;
    short8 wf[3][6];
#pragma unroll
    for (int mt = 0; mt < 3; ++mt)
#pragma unroll
        for (int ks = 0; ks < 6; ++ks)
            wf[mt][ks] = *(const short8*)(Wpg + (r0 + mt * 16) * 192 + ks * 32 + kc);

    // A_scale (GEMM1 B) fragments
    const int ncol = wid * 16 + lam;
    const short8 bq0 = *(const short8*)(bsTg + ncol * 72 + kc);
    const short8 bq1 = *(const short8*)(bsTg + ncol * 72 + 32 + kc);

    // per-lane fused bias (o = r0 + mt*16)
    float bb[3];
#pragma unroll
    for (int mt = 0; mt < 3; ++mt) bb[mt] = bbg[r0 + mt * 16];

    // zero the u=50..63 pad once per slot (stage never touches it)
    for (int idx = tid; idx < 1344; idx += 256) {
        int r = idx / 7, k = idx - r * 7;
        int slot = r / 96, c = r - 96 * slot;
        *(unsigned int*)(xsb + ((slot * 12288 + c * 128 + (50 + 2 * k) * 2) ^ ((c & 7) << 4))) = 0;
    }

    stpair(xsb, 0, pf, tid);        // t0 -> slot0
    ldpair(x, gb0 + 50, pf, tid);   // t1
    stpair(xsb, 1, pf, tid);        // t1 -> slot1
    __syncthreads();

    const f32x4 z = {0.f, 0.f, 0.f, 0.f};
    const int s = ncol >= 25 ? 1 : 0;
    const int vs = ncol - 25 * s;

#pragma unroll 1
    for (int tl = 0; tl < 4; ++tl) {
        const int slot = tl & 1;
        // ---- GEMM1: agg(96x50) for timestep t0+tl ----
        f32x4 acc1[6];
#pragma unroll
        for (int mt = 0; mt < 6; ++mt) acc1[mt] = z;
#pragma unroll
        for (int ks = 0; ks < 2; ++ks) {
#pragma unroll
            for (int mt = 0; mt < 6; ++mt) {
                int c = mt * 16 + lam;
                const short8 afr = *(const short8*)(xsb +
                    ((slot * 12288 + c * 128 + (ks * 32 + kc) * 2) ^ ((c & 7) << 4)));
                acc1[mt] = __builtin_amdgcn_mfma_f32_16x16x32_bf16(
                    afr, ks ? bq1 : bq0, acc1[mt], 0, 0, 0);
            }
        }
        if (ncol < 50) {
#pragma unroll
            for (int mt = 0; mt < 6; ++mt)
                *(short4v*)(&a2T[vs][s * 96 + mt * 16 + cb]) =
                    cvt4(acc1[mt][0], acc1[mt][1], acc1[mt][2], acc1[mt][3]);
        }
        __syncthreads();   // bar1: a2T visible; all waves done reading slot

        // T14: issue next-next timestep's loads now; LDS-write after GEMM2
        if (tl < 2) ldpair(x, gb0 + (tl + 2) * 50, pf, tid);

        // ---- GEMM2 (flipped): D[tv][o] for this timestep ----
        f32x4 acc[3][2];
#pragma unroll
        for (int mt = 0; mt < 3; ++mt) { acc[mt][0] = z; acc[mt][1] = z; }
#pragma unroll
        for (int ks = 0; ks < 6; ++ks) {
            const short8 A0 = *(const short8*)(&a2T[lam][ks * 32 + kc]);        // tv 0..15
            const short8 A1 = *(const short8*)(&a2T[16 + lam][ks * 32 + kc]);   // tv 16..31
#pragma unroll
            for (int mt = 0; mt < 3; ++mt) {
                acc[mt][0] = __builtin_amdgcn_mfma_f32_16x16x32_bf16(A0, wf[mt][ks], acc[mt][0], 0, 0, 0);
                acc[mt][1] = __builtin_amdgcn_mfma_f32_16x16x32_bf16(A1, wf[mt][ks], acc[mt][1], 0, 0, 0);
            }
        }

        if (tl < 2) stpair(xsb, slot, pf, tid);   // write t+2 into freed slot

        // ---- epilogue: contiguous per-lane stores ----
        const int t = t0 + tl;
#pragma unroll
        for (int mt = 0; mt < 3; ++mt) {
            float* op = out + ((size_t)(n * 192 + r0 + mt * 16)) * 7500 + t * 25;
#pragma unroll
            for (int r = 0; r < 4; ++r) {               // tv = cb+r (<25 always)
                float v = acc[mt][0][r] + bb[mt];
                op[cb + r] = v > 0.f ? v : 0.f;
            }
#pragma unroll
            for (int r = 0; r < 4; ++r) {               // tv = 16+cb+r
                int tv = 16 + cb + r;
                if (tv < 25) {
                    float v = acc[mt][1][r] + bb[mt];
                    op[tv] = v > 0.f ? v : 0.f;
                }
            }
        }
        if (tl < 3) __syncthreads();   // bar2: a2T WAR + restaged slot visible
    }
}

// ---------------------------------------------------------------------------
extern "C" void kernel_launch(void* const* d_in, const int* in_sizes, int n_in,
                              void* d_out, int out_size, void* d_ws, size_t ws_size,
                              hipStream_t stream) {
    const float* x     = (const float*)d_in[0];
    const float* xx    = (const float*)d_in[1];
    const float* A_res = (const float*)d_in[2];
    const float* W     = (const float*)d_in[3];
    const float* b     = (const float*)d_in[4];
    const float* gamma = (const float*)d_in[5];
    const float* beta  = (const float*)d_in[6];
    const float* rm    = (const float*)d_in[7];
    const float* rv    = (const float*)d_in[8];
    float* out = (float*)d_out;

    char* ws = (char*)d_ws;
    float* At_part  = (float*)ws;                    // 160*625*4 = 400000 B
    float* Acontrib = (float*)(ws + 400000);         // 32*625*4  =  80000 B
    short* bsTg     = (short*)(ws + 480000);         // 64*72*2   =   9216 B
    short* Wpg      = (short*)(ws + 489216);         // 192*192*2 =  73728 B
    float* bbg      = (float*)(ws + 562944);         // 192*4     =    768 B

    kA<<<dim3(5, 32), 256, 0, stream>>>(xx, At_part);
    kB1<<<32, 256, 0, stream>>>(At_part, Acontrib);
    kB2<<<37, 256, 0, stream>>>(Acontrib, A_res, W, b, gamma, beta, rm, rv, bsTg, Wpg, bbg);
    kC<<<dim3(75, 32), 256, 0, stream>>>(x, Wpg, bsTg, bbg, out);
}

// Round 8
// 215.661 us; speedup vs baseline: 1.6577x; 1.2354x over previous
//
#include <hip/hip_runtime.h>
#include <hip/hip_bf16.h>

typedef __attribute__((ext_vector_type(8))) short short8;
typedef __attribute__((ext_vector_type(4))) short short4v;
typedef __attribute__((ext_vector_type(4))) float f32x4;
typedef __attribute__((ext_vector_type(2))) float f32x2;

__device__ __forceinline__ unsigned short f2bf(float f) {
    unsigned int u = __builtin_bit_cast(unsigned int, f);
    u += 0x7fffu + ((u >> 16) & 1u);   // round-to-nearest-even
    return (unsigned short)(u >> 16);
}
__device__ __forceinline__ unsigned int pack2(float a, float b) {
    union { __hip_bfloat162 h; unsigned int u; } r;
    r.h = __float22bfloat162_rn(make_float2(a, b));
    return r.u;
}
__device__ __forceinline__ short4v cvt4(float a, float b, float c, float d) {
    union { __hip_bfloat162 h[2]; short4v s; } u;
    u.h[0] = __float22bfloat162_rn(make_float2(a, b));
    u.h[1] = __float22bfloat162_rn(make_float2(c, d));
    return u.s;
}

// ---------------------------------------------------------------------------
// Kernel A: partial adjacency sums over 60-frame chunks. grid (5,32).
// ---------------------------------------------------------------------------
__global__ void kA(const float* __restrict__ xx, float* __restrict__ At_part) {
    __shared__ float xs3[3][60][25];
    const int tc = blockIdx.x, n = blockIdx.y;
    const int tid = threadIdx.x;
    const float* base = xx + (size_t)n * 22500 + tc * 1500;
    for (int idx = tid; idx < 4500; idx += 256) {
        int ch = idx / 1500, rt = idx % 1500;
        xs3[ch][rt / 25][rt % 25] = base[ch * 7500 + rt];
    }
    __syncthreads();
    for (int p = tid; p < 625; p += 256) {
        int v = p / 25, u = p % 25;
        float s = 0.f;
        for (int t = 0; t < 60; ++t) {
            float dx = xs3[0][t][v] - xs3[0][t][u];
            float dy = xs3[1][t][v] - xs3[1][t][u];
            float dz = xs3[2][t][v] - xs3[2][t][u];
            s += __expf(-2.f * (dx * dx + dy * dy + dz * dz));
        }
        At_part[(size_t)(n * 5 + tc) * 625 + p] = s;
    }
}

// ---------------------------------------------------------------------------
// Kernel B1: per-sample reduce + symmetric normalization. grid 32.
// ---------------------------------------------------------------------------
__global__ void kB1(const float* __restrict__ At_part, float* __restrict__ Acontrib) {
    __shared__ float At[625];
    __shared__ float dinv[25];
    const int n = blockIdx.x, tid = threadIdx.x;
    for (int p = tid; p < 625; p += 256) {
        float s = 0.f;
        for (int tc = 0; tc < 5; ++tc) s += At_part[(size_t)(n * 5 + tc) * 625 + p];
        At[p] = s;
    }
    __syncthreads();
    if (tid < 25) {
        float d = 0.f;
        for (int u = 0; u < 25; ++u) d += At[tid * 25 + u];
        dinv[tid] = rsqrtf(d * (1.f / 300.f));
    }
    __syncthreads();
    for (int p = tid; p < 625; p += 256)
        Acontrib[n * 625 + p] = At[p] * (1.f / 300.f) * dinv[p / 25] * dinv[p % 25] * (1.f / 32.f);
}

// ---------------------------------------------------------------------------
// Kernel B2: block 0 -> bsTg (bf16 [64][72], zero-padded) + fused bias;
//            blocks 1..36 -> W'' = W * bn_scale  (layout [o][k], row-major).
// ---------------------------------------------------------------------------
__global__ void kB2(const float* __restrict__ Acontrib, const float* __restrict__ A_res,
                    const float* __restrict__ W, const float* __restrict__ b,
                    const float* __restrict__ gamma, const float* __restrict__ beta,
                    const float* __restrict__ rm, const float* __restrict__ rv,
                    short* __restrict__ bsTg, short* __restrict__ Wpg,
                    float* __restrict__ bbg) {
    const int tid = threadIdx.x;
    if (blockIdx.x == 0) {
        __shared__ float macc[625];
        for (int p = tid; p < 625; p += 256) {
            float s = 0.f;
            for (int n = 0; n < 32; ++n) s += Acontrib[n * 625 + p];
            macc[p] = s;
        }
        __syncthreads();
        for (int idx = tid; idx < 64 * 72; idx += 256) {
            int col = idx / 72, u = idx % 72;
            float v = 0.f;
            if (col < 50 && u < 50) v = macc[(col % 25) * 25 + (u % 25)] + A_res[col * 50 + u];
            bsTg[idx] = (short)f2bf(v);
        }
        if (tid < 192) {
            float sc = gamma[tid] * rsqrtf(rv[tid] + 1e-5f);
            bbg[tid] = b[tid] * sc + beta[tid] - rm[tid] * sc;
        }
    } else {
        const int e = (blockIdx.x - 1) * 1024 + tid * 4;
        const int o = e / 192;
        const float sc = gamma[o] * rsqrtf(rv[o] + 1e-5f);
        float4 w = *(const float4*)(W + e);
        short4v s4 = { (short)f2bf(w.x * sc), (short)f2bf(w.y * sc),
                       (short)f2bf(w.z * sc), (short)f2bf(w.w * sc) };
        *(short4v*)(Wpg + e) = s4;
    }
}

// ---------------------------------------------------------------------------
// Kernel C helpers: one timestep = 96 rows x 50 floats = 2400 f32x2.
// ---------------------------------------------------------------------------
__device__ __forceinline__ void ldpair(const float* __restrict__ x, int gbase,
                                       f32x2 (&pf)[10], int tid) {
#pragma unroll
    for (int i = 0; i < 10; ++i) {
        int idx = i * 256 + tid;
        idx = idx < 2400 ? idx : 2399;
        int c = idx / 25, q = idx - c * 25;
        pf[i] = *(const f32x2*)(x + gbase + (size_t)c * 15000 + 2 * q);
    }
}
__device__ __forceinline__ void stpair(char* xsb, int slot, const f32x2 (&pf)[10], int tid) {
#pragma unroll
    for (int i = 0; i < 10; ++i) {
        int idx = i * 256 + tid;
        if (idx < 2400) {
            int c = idx / 25, q = idx - c * 25;
            *(unsigned int*)(xsb + ((slot * 12288 + c * 128 + 4 * q) ^ ((c & 7) << 4)))
                = pack2(pf[i].x, pf[i].y);
        }
    }
}

// ---------------------------------------------------------------------------
// Kernel C: fused graph-conv + 1x1 conv + BN + ReLU.
// grid (75, 32) natural order.  4 timesteps/block, 2-slot per-t staging
// (issue loads early / LDS-write late).  Flipped GEMM2 -> contiguous stores.
// W'' fragments are STREAMED from L2 inside the ks-loop (not preloaded):
// cuts ~72 resident VGPRs -> fits the (256,3) 168-reg budget without spill
// (the R4-R7 failure mode: spill scratch traffic = +200 MB WRITE).
// LDS 37.4 KB -> 3 blocks/CU, 12 waves/CU.
// ---------------------------------------------------------------------------
__global__ __launch_bounds__(256, 3)
void kC(const float* __restrict__ x, const short* __restrict__ Wpg,
        const short* __restrict__ bsTg, const float* __restrict__ bbg,
        float* __restrict__ out) {
    __shared__ __align__(16) char xsb[2 * 12288];      // 2 one-timestep slots
    __shared__ __align__(16) short a2T[32][200];       // 12800 B (rows 25..31 pad)

    const int tid = threadIdx.x;
    const int lane = tid & 63;
    const int wid = tid >> 6;
    const int lam = lane & 15;
    const int kc = (lane >> 4) * 8;
    const int cb = (lane >> 4) * 4;
    const int n = blockIdx.y;
    const int t0 = blockIdx.x * 4;
    const int gb0 = n * 1440000 + t0 * 50;

    // prefetch t0 (longest latency first)
    f32x2 pf[10];
    ldpair(x, gb0, pf, tid);

    // A_scale (GEMM1 B) fragments
    const int ncol = wid * 16 + lam;
    const short8 bq0 = *(const short8*)(bsTg + ncol * 72 + kc);
    const short8 bq1 = *(const short8*)(bsTg + ncol * 72 + 32 + kc);

    // per-lane fused bias (o = r0 + mt*16)
    const int r0 = wid * 48 + lam;
    float bb[3];
#pragma unroll
    for (int mt = 0; mt < 3; ++mt) bb[mt] = bbg[r0 + mt * 16];

    // GEMM2 B-operand base: row r0, k-offset kc (streamed per ks)
    const short* wbase = Wpg + r0 * 192 + kc;

    // zero the u=50..63 pad once per slot (stage never touches it)
    for (int idx = tid; idx < 1344; idx += 256) {
        int r = idx / 7, k = idx - r * 7;
        int slot = r / 96, c = r - 96 * slot;
        *(unsigned int*)(xsb + ((slot * 12288 + c * 128 + (50 + 2 * k) * 2) ^ ((c & 7) << 4))) = 0;
    }

    stpair(xsb, 0, pf, tid);        // t0 -> slot0
    ldpair(x, gb0 + 50, pf, tid);   // t1
    stpair(xsb, 1, pf, tid);        // t1 -> slot1
    __syncthreads();

    const f32x4 z = {0.f, 0.f, 0.f, 0.f};
    const int s = ncol >= 25 ? 1 : 0;
    const int vs = ncol - 25 * s;

#pragma unroll 1
    for (int tl = 0; tl < 4; ++tl) {
        const int slot = tl & 1;
        // ---- GEMM1: agg(96x50) for timestep t0+tl ----
        f32x4 acc1[6];
#pragma unroll
        for (int mt = 0; mt < 6; ++mt) acc1[mt] = z;
#pragma unroll
        for (int ks = 0; ks < 2; ++ks) {
#pragma unroll
            for (int mt = 0; mt < 6; ++mt) {
                int c = mt * 16 + lam;
                const short8 afr = *(const short8*)(xsb +
                    ((slot * 12288 + c * 128 + (ks * 32 + kc) * 2) ^ ((c & 7) << 4)));
                acc1[mt] = __builtin_amdgcn_mfma_f32_16x16x32_bf16(
                    afr, ks ? bq1 : bq0, acc1[mt], 0, 0, 0);
            }
        }
        if (ncol < 50) {
#pragma unroll
            for (int mt = 0; mt < 6; ++mt)
                *(short4v*)(&a2T[vs][s * 96 + mt * 16 + cb]) =
                    cvt4(acc1[mt][0], acc1[mt][1], acc1[mt][2], acc1[mt][3]);
        }
        __syncthreads();   // bar1: a2T visible; all waves done reading slot

        // issue next-next timestep's loads now; LDS-write after GEMM2
        if (tl < 2) ldpair(x, gb0 + (tl + 2) * 50, pf, tid);

        // ---- GEMM2 (flipped): D[tv][o], W'' streamed from L2 ----
        f32x4 acc[3][2];
#pragma unroll
        for (int mt = 0; mt < 3; ++mt) { acc[mt][0] = z; acc[mt][1] = z; }
#pragma unroll 2
        for (int ks = 0; ks < 6; ++ks) {
            const short8 A0 = *(const short8*)(&a2T[lam][ks * 32 + kc]);        // tv 0..15
            const short8 A1 = *(const short8*)(&a2T[16 + lam][ks * 32 + kc]);   // tv 16..31
            const short8 w0 = *(const short8*)(wbase + ks * 32);
            const short8 w1 = *(const short8*)(wbase + 16 * 192 + ks * 32);
            const short8 w2 = *(const short8*)(wbase + 32 * 192 + ks * 32);
            acc[0][0] = __builtin_amdgcn_mfma_f32_16x16x32_bf16(A0, w0, acc[0][0], 0, 0, 0);
            acc[0][1] = __builtin_amdgcn_mfma_f32_16x16x32_bf16(A1, w0, acc[0][1], 0, 0, 0);
            acc[1][0] = __builtin_amdgcn_mfma_f32_16x16x32_bf16(A0, w1, acc[1][0], 0, 0, 0);
            acc[1][1] = __builtin_amdgcn_mfma_f32_16x16x32_bf16(A1, w1, acc[1][1], 0, 0, 0);
            acc[2][0] = __builtin_amdgcn_mfma_f32_16x16x32_bf16(A0, w2, acc[2][0], 0, 0, 0);
            acc[2][1] = __builtin_amdgcn_mfma_f32_16x16x32_bf16(A1, w2, acc[2][1], 0, 0, 0);
        }

        if (tl < 2) stpair(xsb, slot, pf, tid);   // write t+2 into freed slot

        // ---- epilogue: contiguous per-lane stores ----
        const int t = t0 + tl;
#pragma unroll
        for (int mt = 0; mt < 3; ++mt) {
            float* op = out + ((size_t)(n * 192 + r0 + mt * 16)) * 7500 + t * 25;
#pragma unroll
            for (int r = 0; r < 4; ++r) {               // tv = cb+r (<25 always)
                float v = acc[mt][0][r] + bb[mt];
                op[cb + r] = v > 0.f ? v : 0.f;
            }
#pragma unroll
            for (int r = 0; r < 4; ++r) {               // tv = 16+cb+r
                int tv = 16 + cb + r;
                if (tv < 25) {
                    float v = acc[mt][1][r] + bb[mt];
                    op[tv] = v > 0.f ? v : 0.f;
                }
            }
        }
        if (tl < 3) __syncthreads();   // bar2: a2T WAR + restaged slot visible
    }
}

// ---------------------------------------------------------------------------
extern "C" void kernel_launch(void* const* d_in, const int* in_sizes, int n_in,
                              void* d_out, int out_size, void* d_ws, size_t ws_size,
                              hipStream_t stream) {
    const float* x     = (const float*)d_in[0];
    const float* xx    = (const float*)d_in[1];
    const float* A_res = (const float*)d_in[2];
    const float* W     = (const float*)d_in[3];
    const float* b     = (const float*)d_in[4];
    const float* gamma = (const float*)d_in[5];
    const float* beta  = (const float*)d_in[6];
    const float* rm    = (const float*)d_in[7];
    const float* rv    = (const float*)d_in[8];
    float* out = (float*)d_out;

    char* ws = (char*)d_ws;
    float* At_part  = (float*)ws;                    // 160*625*4 = 400000 B
    float* Acontrib = (float*)(ws + 400000);         // 32*625*4  =  80000 B
    short* bsTg     = (short*)(ws + 480000);         // 64*72*2   =   9216 B
    short* Wpg      = (short*)(ws + 489216);         // 192*192*2 =  73728 B
    float* bbg      = (float*)(ws + 562944);         // 192*4     =    768 B

    kA<<<dim3(5, 32), 256, 0, stream>>>(xx, At_part);
    kB1<<<32, 256, 0, stream>>>(At_part, Acontrib);
    kB2<<<37, 256, 0, stream>>>(Acontrib, A_res, W, b, gamma, beta, rm, rv, bsTg, Wpg, bbg);
    kC<<<dim3(75, 32), 256, 0, stream>>>(x, Wpg, bsTg, bbg, out);
}